// Round 1
// baseline (347.001 us; speedup 1.0000x reference)
//
#include <hip/hip_runtime.h>

// sbvr decode: decoded[g,l] = sum_s coeff_cache[coeff_idx[g], s] * ((bvr[g,s]>>l)&1)
// G = 4,194,304 groups, S = 4 sums, L = 16 elements/group, out = 64M fp32 (256 MB).
// Memory-bound: ~336 MB compulsory traffic -> ~53 us floor at 6.3 TB/s.
//
// v2: MLP batching. The v1 kernel gave each thread exactly ONE item, so each
// wave's lifetime was one serial chain: idx load (HBM ~900cy) -> table gather
// (L1-miss -> L2 ~300cy) -> compute -> store, with a single outstanding idx
// load per wave slot. That is latency-bound (~throughput = occupancy/latency),
// not BW-bound. Here each thread processes ITEMS=4 independent quarter-groups:
// all 4 idx loads issued together, then all 4 bvr loads, then all 4 gathers.
// 4x outstanding loads per wave slot -> latency ceiling drops ~4x, pushing the
// kernel to the HBM roofline.
//
// Item k of thread tid = blockBase + k*BLOCK + tid, so every load/store
// instruction stays fully lane-contiguous (store coalescing unchanged; stores
// are 256 MB of the 336 MB traffic).
//
// NOTE: __builtin_nontemporal_* requires native ext_vector_type, not the
// HIP_vector_type structs (int4/float4) — hence i32x4/f32x4 below.

#define NUM_SUMS 4
#define BVR_LEN 16

typedef int   i32x4 __attribute__((ext_vector_type(4)));
typedef float f32x4 __attribute__((ext_vector_type(4)));

static constexpr int TOTAL_ITEMS = (8192 * 8192) / 4;  // 16,777,216 quarter-groups
static constexpr int BLOCK = 256;
static constexpr int ITEMS = 4;                         // independent items per thread
static constexpr int GRID  = TOTAL_ITEMS / (BLOCK * ITEMS);  // 16384 blocks

__global__ __launch_bounds__(BLOCK) void sbvr_decode_kernel(
        const float* __restrict__ coeff_cache,   // [65536, 4]
        const int*   __restrict__ coeff_idx,     // [G]
        const int*   __restrict__ bvr,           // [G, 4]
        float*       __restrict__ out)           // [G * 16]
{
    const int base = blockIdx.x * (BLOCK * ITEMS) + threadIdx.x;
    const int q4   = (threadIdx.x & 3) * 4;      // first bit index (same for all k)

    int t[ITEMS];
#pragma unroll
    for (int k = 0; k < ITEMS; ++k) t[k] = base + k * BLOCK;

    // Phase 1: all idx loads in flight (streamed once -> nontemporal).
    int idx[ITEMS];
#pragma unroll
    for (int k = 0; k < ITEMS; ++k)
        idx[k] = __builtin_nontemporal_load(coeff_idx + (t[k] >> 2));

    // Phase 2: all bvr loads in flight (independent of idx).
    i32x4 b[ITEMS];
#pragma unroll
    for (int k = 0; k < ITEMS; ++k)
        b[k] = __builtin_nontemporal_load((const i32x4*)bvr + (t[k] >> 2));

    // Phase 3: all table gathers in flight (cached: 1 MB table stays L2-resident).
    f32x4 c[ITEMS];
#pragma unroll
    for (int k = 0; k < ITEMS; ++k)
        c[k] = ((const f32x4*)coeff_cache)[idx[k]];

    // Phase 4: compute + store, per item.
#pragma unroll
    for (int k = 0; k < ITEMS; ++k) {
        f32x4 r;
#pragma unroll
        for (int j = 0; j < 4; ++j) {
            const int l = q4 + j;
            // accumulate in the reference's s-order (s = 0..3) in fp32
            float acc = ((b[k].x >> l) & 1) ? c[k].x : 0.0f;
            acc      += ((b[k].y >> l) & 1) ? c[k].y : 0.0f;
            acc      += ((b[k].z >> l) & 1) ? c[k].z : 0.0f;
            acc      += ((b[k].w >> l) & 1) ? c[k].w : 0.0f;
            r[j] = acc;
        }
        __builtin_nontemporal_store(r, (f32x4*)out + t[k]);
    }
}

extern "C" void kernel_launch(void* const* d_in, const int* in_sizes, int n_in,
                              void* d_out, int out_size, void* d_ws, size_t ws_size,
                              hipStream_t stream) {
    const float* coeff_cache = (const float*)d_in[0];
    const int*   coeff_idx   = (const int*)d_in[1];
    const int*   bvr         = (const int*)d_in[2];
    float*       out         = (float*)d_out;

    sbvr_decode_kernel<<<GRID, BLOCK, 0, stream>>>(coeff_cache, coeff_idx, bvr, out);
}